// Round 1
// baseline (561.230 us; speedup 1.0000x reference)
//
#include <hip/hip_runtime.h>
#include <math.h>

// ---------------------------------------------------------------------------
// Performer encoder layer, MI355X round-0 baseline.
// N=8192, D=512, H=8, DH=64, NF=266 (padded to NFP=320 = 5*64).
// Workspace layout (bytes):
//   0        wtqkv  bf16 [3][512][512]   (wq^T,wk^T,wv^T)
//   1572864  wot    bf16 [512][512]
//   2097152  w1t    bf16 [2048][512]
//   4194304  w2t    bf16 [512][2048]
//   6291456  projb  bf16 [320][64]  (proj*dnorm, zero rows >=266)
//   6332416  h_bf   bf16 [8192][512]     (also reused as attn_bf)
//   14721024 qkv    bf16 [3][8192][512]  (also reused as h2_bf)
//   39886848 diag   f32  [2][8][8192]
//   40411136 qp     bf16 [8][8192][320]
//   82354176 kp     bf16 [8][8192][320]
//   124297216 mk    u32  [8] (encoded f32 max)
//   124297472 kps_part f32 [8][32][320]
//   124625152 ctx_part f32 [8][8][64][320]
//   129868032 ksum  f32  [8][320]
//   129878272 ctxbf bf16 [8][64][320]   (context^T per head: [d][j])
//   130205952 dinv  f32  [8][8192]
//   130468096 gbf   bf16 [8192][2048]
//   total ~164 MB.  xb (f32 [8192][512]) lives in d_out.
// ---------------------------------------------------------------------------

typedef __attribute__((ext_vector_type(8))) short bf16x8;
typedef __attribute__((ext_vector_type(4))) float f32x4;

#define N_SEQ 8192
#define DMODEL 512
#define NHEAD 8
#define DHEAD 64
#define NF 266
#define NFP 320
#define PEPS 1e-4f
#define LNEPS 1e-5f
#define DNORM 0.35355339059327373f
#define RATIO 0.06131393694f

__device__ __forceinline__ unsigned short f2bf(float f) {
  unsigned u = __float_as_uint(f);
  u += 0x7FFFu + ((u >> 16) & 1u);
  return (unsigned short)(u >> 16);
}
__device__ __forceinline__ float bf2f(unsigned short b) {
  return __uint_as_float(((unsigned)b) << 16);
}
__device__ __forceinline__ unsigned enc_f32(float f) {
  unsigned i = __float_as_uint(f);
  return (i & 0x80000000u) ? ~i : (i | 0x80000000u);
}
__device__ __forceinline__ float dec_f32(unsigned u) {
  return (u & 0x80000000u) ? __uint_as_float(u & 0x7FFFFFFFu) : __uint_as_float(~u);
}

// -------------------- small prep kernels --------------------

__global__ void init_mk_kernel(unsigned* mk) {
  if (threadIdx.x < NHEAD) mk[threadIdx.x] = 0x007FFFFFu;  // enc(-inf)
}

// dst[c][r] = bf16(src[r][c]); src is [R][C] f32. grid (C/32, R/32), block (32,8)
__global__ __launch_bounds__(256) void transpose_w_kernel(const float* __restrict__ src,
                                                          unsigned short* __restrict__ dst,
                                                          int R, int C) {
  __shared__ float tile[32][33];
  int c0 = blockIdx.x * 32, r0 = blockIdx.y * 32;
  int tx = threadIdx.x, ty = threadIdx.y;
  #pragma unroll
  for (int i = ty; i < 32; i += 8)
    tile[i][tx] = src[(long)(r0 + i) * C + c0 + tx];
  __syncthreads();
  #pragma unroll
  for (int i = ty; i < 32; i += 8)
    dst[(long)(c0 + i) * R + r0 + tx] = f2bf(tile[tx][i]);
}

__global__ void projb_kernel(const float* __restrict__ proj, unsigned short* __restrict__ pb) {
  int id = blockIdx.x * 256 + threadIdx.x;  // < 320*64
  int j = id >> 6;
  pb[id] = (j < NF) ? f2bf(proj[(long)j * 64 + (id & 63)] * DNORM) : (unsigned short)0;
}

// -------------------- layernorm --------------------

__global__ __launch_bounds__(256) void ln_kernel(const float* __restrict__ x,
                                                 const float* __restrict__ g,
                                                 const float* __restrict__ b,
                                                 unsigned short* __restrict__ out) {
  __shared__ float sred[4];
  int row = blockIdx.x, t = threadIdx.x;
  float2 v = ((const float2*)(x + (long)row * DMODEL))[t];
  float s = v.x + v.y;
  #pragma unroll
  for (int m = 32; m >= 1; m >>= 1) s += __shfl_xor(s, m);
  if ((t & 63) == 0) sred[t >> 6] = s;
  __syncthreads();
  float mu = (sred[0] + sred[1] + sred[2] + sred[3]) * (1.0f / DMODEL);
  __syncthreads();
  float d0 = v.x - mu, d1 = v.y - mu;
  float q = d0 * d0 + d1 * d1;
  #pragma unroll
  for (int m = 32; m >= 1; m >>= 1) q += __shfl_xor(q, m);
  if ((t & 63) == 0) sred[t >> 6] = q;
  __syncthreads();
  float var = (sred[0] + sred[1] + sred[2] + sred[3]) * (1.0f / DMODEL);
  float inv = rsqrtf(var + LNEPS);
  int c = t * 2;
  unsigned short o0 = f2bf(d0 * inv * g[c] + b[c]);
  unsigned short o1 = f2bf(d1 * inv * g[c + 1] + b[c + 1]);
  ((unsigned*)(out + (long)row * DMODEL))[t] = ((unsigned)o1 << 16) | o0;
}

// -------------------- generic bf16 MFMA GEMM --------------------
// C[M,N] = A[M,K](bf16 row-major) x Bt[N,K]^T (bf16 row-major = B^T), fp32 acc.
// 256 threads = 4 waves. BK=64 with XOR swizzle ((chunk)^(row&7)) on 16B chunks.
// A-frag: row = lane&15, k = 32*ks + 8*(lane>>4)+i.  C/D: col=lane&15,
// row=(lane>>4)*4+reg (HW-verified layout).

enum { EPI_BF16 = 0, EPI_DINV = 1, EPI_BIAS_RES_F32 = 2, EPI_BIAS_GELU = 3 };

template <int BM, int BN, int WM, int WN, int EPI>
__global__ __launch_bounds__(256) void gemm_kernel(
    const unsigned short* __restrict__ A, int lda, long sA,
    const unsigned short* __restrict__ Bt, int ldb, long sB,
    void* __restrict__ Cv, int ldc, long sC,
    int K,
    const float* __restrict__ bias,
    const float* __restrict__ res, int ldr,
    const float* __restrict__ dinv, long sDinv) {
  constexpr int BK = 64;
  static_assert((BM / WM) * (BN / WN) == 4, "need 4 waves");
  constexpr int MR = WM / 16, NR = WN / 16;
  constexpr int WNN = BN / WN;
  const int tid = threadIdx.x;
  const int wave = tid >> 6, lane = tid & 63;
  const int lr = lane & 15, lg = lane >> 4;
  const int wr = wave / WNN, wc = wave % WNN;
  const int m0 = blockIdx.x * BM, n0 = blockIdx.y * BN;
  const int z = blockIdx.z;
  A += (long)z * sA;
  Bt += (long)z * sB;

  __shared__ uint4 a_s4[BM * 8];
  __shared__ uint4 b_s4[BN * 8];

  f32x4 acc[MR][NR] = {};

  for (int k0 = 0; k0 < K; k0 += BK) {
    constexpr int AIT = BM * 8 / 256;
    #pragma unroll
    for (int e = 0; e < AIT; ++e) {
      int qq = tid * AIT + e;
      int r = qq >> 3, c = qq & 7;
      a_s4[r * 8 + (c ^ (r & 7))] = *(const uint4*)(A + (long)(m0 + r) * lda + k0 + c * 8);
    }
    constexpr int BIT = BN * 8 / 256;
    #pragma unroll
    for (int e = 0; e < BIT; ++e) {
      int qq = tid * BIT + e;
      int r = qq >> 3, c = qq & 7;
      b_s4[r * 8 + (c ^ (r & 7))] = *(const uint4*)(Bt + (long)(n0 + r) * ldb + k0 + c * 8);
    }
    __syncthreads();
    #pragma unroll
    for (int ks = 0; ks < 2; ++ks) {
      bf16x8 af[MR], bv[NR];
      #pragma unroll
      for (int i = 0; i < MR; ++i) {
        int r = wr * WM + i * 16 + lr;
        af[i] = *(const bf16x8*)&a_s4[r * 8 + ((ks * 4 + lg) ^ (r & 7))];
      }
      #pragma unroll
      for (int j = 0; j < NR; ++j) {
        int r = wc * WN + j * 16 + lr;
        bv[j] = *(const bf16x8*)&b_s4[r * 8 + ((ks * 4 + lg) ^ (r & 7))];
      }
      #pragma unroll
      for (int i = 0; i < MR; ++i)
        #pragma unroll
        for (int j = 0; j < NR; ++j)
          acc[i][j] = __builtin_amdgcn_mfma_f32_16x16x32_bf16(af[i], bv[j], acc[i][j], 0, 0, 0);
    }
    __syncthreads();
  }

  #pragma unroll
  for (int i = 0; i < MR; ++i) {
    #pragma unroll
    for (int j = 0; j < NR; ++j) {
      int gn = n0 + wc * WN + j * 16 + lr;
      #pragma unroll
      for (int rg = 0; rg < 4; ++rg) {
        int gm = m0 + wr * WM + i * 16 + lg * 4 + rg;
        float v = acc[i][j][rg];
        if (EPI == EPI_BF16) {
          ((unsigned short*)Cv)[(long)z * sC + (long)gm * ldc + gn] = f2bf(v);
        } else if (EPI == EPI_DINV) {
          v *= dinv[(long)z * sDinv + gm];
          ((unsigned short*)Cv)[(long)z * sC + (long)gm * ldc + gn] = f2bf(v);
        } else if (EPI == EPI_BIAS_RES_F32) {
          v += bias[gn] + res[(long)gm * ldr + gn];
          ((float*)Cv)[(long)z * sC + (long)gm * ldc + gn] = v;
        } else if (EPI == EPI_BIAS_GELU) {
          v += bias[gn];
          float t3 = 0.7978845608028654f * (v + 0.044715f * v * v * v);
          v = 0.5f * v * (1.0f + tanhf(t3));
          ((unsigned short*)Cv)[(long)z * sC + (long)gm * ldc + gn] = f2bf(v);
        }
      }
    }
  }
}

// -------------------- diag: 0.5*dnorm^2*sum(q^2) --------------------

__global__ __launch_bounds__(256) void diag_kernel(const unsigned short* __restrict__ qkv,
                                                   float* __restrict__ diag) {
  int id = blockIdx.x * 256 + threadIdx.x;  // < 2*8*8192
  int tensor = id >> 16;
  int rem = id & 65535;
  int n = rem >> 3, h = rem & 7;
  const unsigned short* p =
      qkv + (long)tensor * (N_SEQ * DMODEL) + (long)n * DMODEL + h * DHEAD;
  float s = 0.f;
  #pragma unroll
  for (int c = 0; c < 8; ++c) {
    uint4 u = *(const uint4*)(p + c * 8);
    const unsigned short* e = (const unsigned short*)&u;
    #pragma unroll
    for (int i = 0; i < 8; ++i) { float f = bf2f(e[i]); s += f * f; }
  }
  diag[(long)tensor * 65536 + (long)h * N_SEQ + n] = s * 0.0625f;  // *0.5*dnorm^2
}

// -------------------- phi: dd GEMM (K=64, all 320 cols in-block) + epilogue ----
// MODE 0: q (per-row max, exp, write qp). MODE 1: k max pass (atomicMax enc).
// MODE 2: k exp pass (global max).

template <int MODE>
__global__ __launch_bounds__(256) void phi_kernel(
    const unsigned short* __restrict__ QK,  // [8192][512] (q or k base)
    const unsigned short* __restrict__ pb,  // [320][64]
    unsigned short* __restrict__ out,       // [8][8192][320]
    const float* __restrict__ diag,         // [8][8192]
    unsigned* __restrict__ mk) {
  const int tid = threadIdx.x;
  const int wave = tid >> 6, lane = tid & 63;
  const int lr = lane & 15, lg = lane >> 4;
  const int h = blockIdx.z;
  const int m0 = blockIdx.x * 64;

  __shared__ uint4 a_s4[64 * 8];
  __shared__ uint4 b_s4[NFP * 8];
  __shared__ float sred[4];

  const unsigned short* Aq = QK + (long)m0 * DMODEL + h * DHEAD;

  #pragma unroll
  for (int e = 0; e < 2; ++e) {
    int qq = tid * 2 + e;
    int r = qq >> 3, c = qq & 7;
    a_s4[r * 8 + (c ^ (r & 7))] = *(const uint4*)(Aq + (long)r * DMODEL + c * 8);
  }
  #pragma unroll
  for (int e = 0; e < 10; ++e) {
    int qq = tid * 10 + e;
    int r = qq >> 3, c = qq & 7;
    b_s4[r * 8 + (c ^ (r & 7))] = *(const uint4*)(pb + (long)r * DHEAD + c * 8);
  }
  __syncthreads();

  f32x4 acc[20] = {};
  #pragma unroll
  for (int ks = 0; ks < 2; ++ks) {
    int rA = wave * 16 + lr;
    bf16x8 af = *(const bf16x8*)&a_s4[rA * 8 + ((ks * 4 + lg) ^ (rA & 7))];
    #pragma unroll
    for (int j = 0; j < 20; ++j) {
      int rB = j * 16 + lr;
      bf16x8 bv = *(const bf16x8*)&b_s4[rB * 8 + ((ks * 4 + lg) ^ (rB & 7))];
      acc[j] = __builtin_amdgcn_mfma_f32_16x16x32_bf16(af, bv, acc[j], 0, 0, 0);
    }
  }

  const int gmb = m0 + wave * 16 + lg * 4;  // + rg

  if (MODE == 1) {
    float m = -3.0e38f;
    #pragma unroll
    for (int j = 0; j < 17; ++j) {
      bool valid = (j < 16) || (lr < 10);  // col = j*16+lr < 266
      if (valid) {
        #pragma unroll
        for (int rg = 0; rg < 4; ++rg) m = fmaxf(m, acc[j][rg]);
      }
    }
    #pragma unroll
    for (int s = 1; s < 64; s <<= 1) m = fmaxf(m, __shfl_xor(m, s));
    if (lane == 0) sred[wave] = m;
    __syncthreads();
    if (tid == 0) {
      float mm = fmaxf(fmaxf(sred[0], sred[1]), fmaxf(sred[2], sred[3]));
      atomicMax(&mk[h], enc_f32(mm));
    }
    return;
  }

  float mrow[4];
  if (MODE == 0) {
    #pragma unroll
    for (int rg = 0; rg < 4; ++rg) mrow[rg] = -3.0e38f;
    #pragma unroll
    for (int j = 0; j < 17; ++j) {
      bool valid = (j < 16) || (lr < 10);
      if (valid) {
        #pragma unroll
        for (int rg = 0; rg < 4; ++rg) mrow[rg] = fmaxf(mrow[rg], acc[j][rg]);
      }
    }
    #pragma unroll
    for (int s = 1; s < 16; s <<= 1)
      #pragma unroll
      for (int rg = 0; rg < 4; ++rg) mrow[rg] = fmaxf(mrow[rg], __shfl_xor(mrow[rg], s));
  } else {
    float mh = dec_f32(mk[h]);
    #pragma unroll
    for (int rg = 0; rg < 4; ++rg) mrow[rg] = mh;
  }

  float dg[4];
  #pragma unroll
  for (int rg = 0; rg < 4; ++rg) dg[rg] = diag[(long)h * N_SEQ + gmb + rg];

  #pragma unroll
  for (int j = 0; j < 20; ++j) {
    int col = j * 16 + lr;
    #pragma unroll
    for (int rg = 0; rg < 4; ++rg) {
      float v = 0.f;
      if (col < NF) v = RATIO * (expf(acc[j][rg] - dg[rg] - mrow[rg]) + PEPS);
      out[((long)h * N_SEQ + gmb + rg) * NFP + col] = f2bf(v);
    }
  }
}

// -------------------- kp column sums (two-stage, deterministic) -----------

__global__ __launch_bounds__(256) void kpsum_part_kernel(const unsigned short* __restrict__ kp,
                                                         float* __restrict__ part) {
  int nc = blockIdx.x, h = blockIdx.y, t = threadIdx.x;
  const unsigned short* base = kp + ((long)h * N_SEQ + (long)nc * 256) * NFP;
  float s0 = 0.f, s1 = 0.f;
  for (int n = 0; n < 256; ++n) {
    const unsigned short* row = base + (long)n * NFP;
    s0 += bf2f(row[t]);
    if (t < 16) s1 += bf2f(row[256 + t]);
  }
  float* pr = part + ((long)h * 32 + nc) * NFP;
  pr[t] = s0;
  if (t < 16) pr[256 + t] = s1;
}

__global__ void kpsum_reduce_kernel(const float* __restrict__ part, float* __restrict__ ksum) {
  int i = blockIdx.x * 256 + threadIdx.x;
  if (i >= NHEAD * NFP) return;
  int h = i / NFP, j = i % NFP;
  float s = 0.f;
  if (j < 272) {
    #pragma unroll 4
    for (int nc = 0; nc < 32; ++nc) s += part[((long)h * 32 + nc) * NFP + j];
  }
  ksum[i] = s;
}

// -------------------- context^T = (kp^T v)^T per head (two-stage) ---------

__global__ __launch_bounds__(256) void ctx_part_kernel(const unsigned short* __restrict__ kp,
                                                       const unsigned short* __restrict__ v,
                                                       float* __restrict__ part) {
  int jt = blockIdx.x, h = blockIdx.y, nc = blockIdx.z;
  int tj = threadIdx.x & 15, td = threadIdx.x >> 4;
  int j = jt * 16 + tj;
  const unsigned short* kb = kp + ((long)h * N_SEQ + (long)nc * 1024) * NFP + j;
  const unsigned short* vb = v + (long)nc * 1024 * DMODEL + h * DHEAD + td * 4;
  float a0 = 0.f, a1 = 0.f, a2 = 0.f, a3 = 0.f;
  #pragma unroll 4
  for (int n = 0; n < 1024; ++n) {
    float kv = bf2f(kb[(long)n * NFP]);
    uint2 u = *(const uint2*)(vb + (long)n * DMODEL);
    a0 += kv * bf2f((unsigned short)(u.x & 0xFFFF));
    a1 += kv * bf2f((unsigned short)(u.x >> 16));
    a2 += kv * bf2f((unsigned short)(u.y & 0xFFFF));
    a3 += kv * bf2f((unsigned short)(u.y >> 16));
  }
  float* cb = part + (((long)h * 8 + nc) * 64 + td * 4) * NFP + j;
  cb[0] = a0; cb[NFP] = a1; cb[2 * NFP] = a2; cb[3 * NFP] = a3;
}

__global__ void ctx_reduce_kernel(const float* __restrict__ part,
                                  unsigned short* __restrict__ ctxbf) {
  int i = blockIdx.x * 256 + threadIdx.x;  // < 8*64*320
  int h = i / (64 * NFP);
  int rem = i % (64 * NFP);
  int j = rem % NFP;
  float s = 0.f;
  if (j < 272) {
    #pragma unroll
    for (int nc = 0; nc < 8; ++nc)
      s += part[(long)h * 8 * 64 * NFP + (long)nc * 64 * NFP + rem];
  }
  ctxbf[i] = f2bf(s);
}

// -------------------- d_inv = 1 / (qp . ksum) --------------------

__global__ __launch_bounds__(256) void dinv_kernel(const unsigned short* __restrict__ qp,
                                                   const float* __restrict__ ksum,
                                                   float* __restrict__ dinv) {
  __shared__ float ks[NFP];
  int h = blockIdx.y, t = threadIdx.x;
  ks[t] = ksum[h * NFP + t];
  if (t < NFP - 256) ks[256 + t] = ksum[h * NFP + 256 + t];
  __syncthreads();
  int wave = t >> 6, lane = t & 63;
  int n = blockIdx.x * 4 + wave;
  const unsigned short* row = qp + ((long)h * N_SEQ + n) * NFP;
  float s = 0.f;
  {
    uint2 u = ((const uint2*)row)[lane];
    s += bf2f((unsigned short)(u.x & 0xFFFF)) * ks[lane * 4 + 0];
    s += bf2f((unsigned short)(u.x >> 16)) * ks[lane * 4 + 1];
    s += bf2f((unsigned short)(u.y & 0xFFFF)) * ks[lane * 4 + 2];
    s += bf2f((unsigned short)(u.y >> 16)) * ks[lane * 4 + 3];
  }
  if (lane < 4) {
    uint2 u = ((const uint2*)row)[64 + lane];
    int jb = 256 + lane * 4;
    s += bf2f((unsigned short)(u.x & 0xFFFF)) * ks[jb + 0];
    s += bf2f((unsigned short)(u.x >> 16)) * ks[jb + 1];
    s += bf2f((unsigned short)(u.y & 0xFFFF)) * ks[jb + 2];
    s += bf2f((unsigned short)(u.y >> 16)) * ks[jb + 3];
  }
  #pragma unroll
  for (int m = 32; m >= 1; m >>= 1) s += __shfl_xor(s, m);
  if (lane == 0) dinv[(long)h * N_SEQ + n] = 1.0f / s;
}

// -------------------- launch --------------------

extern "C" void kernel_launch(void* const* d_in, const int* in_sizes, int n_in,
                              void* d_out, int out_size, void* d_ws, size_t ws_size,
                              hipStream_t stream) {
  const float* x    = (const float*)d_in[0];
  const float* proj = (const float*)d_in[1];
  const float* ln1g = (const float*)d_in[2];
  const float* ln1b = (const float*)d_in[3];
  const float* wq   = (const float*)d_in[4];
  const float* wk   = (const float*)d_in[5];
  const float* wv   = (const float*)d_in[6];
  const float* wo   = (const float*)d_in[7];
  const float* wob  = (const float*)d_in[8];
  const float* ln2g = (const float*)d_in[9];
  const float* ln2b = (const float*)d_in[10];
  const float* w1   = (const float*)d_in[11];
  const float* b1   = (const float*)d_in[12];
  const float* w2   = (const float*)d_in[13];
  const float* b2   = (const float*)d_in[14];

  char* ws = (char*)d_ws;
  unsigned short* wtqkv = (unsigned short*)(ws + 0);
  unsigned short* wot   = (unsigned short*)(ws + 1572864);
  unsigned short* w1t   = (unsigned short*)(ws + 2097152);
  unsigned short* w2t   = (unsigned short*)(ws + 4194304);
  unsigned short* pb    = (unsigned short*)(ws + 6291456);
  unsigned short* h_bf  = (unsigned short*)(ws + 6332416);
  unsigned short* qkv   = (unsigned short*)(ws + 14721024);
  float* diag           = (float*)(ws + 39886848);
  unsigned short* qp    = (unsigned short*)(ws + 40411136);
  unsigned short* kp    = (unsigned short*)(ws + 82354176);
  unsigned* mk          = (unsigned*)(ws + 124297216);
  float* kps_part       = (float*)(ws + 124297472);
  float* ctx_part       = (float*)(ws + 124625152);
  float* ksum           = (float*)(ws + 129868032);
  unsigned short* ctxbf = (unsigned short*)(ws + 129878272);
  float* dinv           = (float*)(ws + 130205952);
  unsigned short* gbf   = (unsigned short*)(ws + 130468096);
  unsigned short* attn  = h_bf;  // reuse (h_bf dead after QKV GEMM)
  unsigned short* h2    = qkv;   // reuse (qkv dead after phi/ctx)
  float* xb             = (float*)d_out;

  dim3 blk(256);

  transpose_w_kernel<<<dim3(16, 16), dim3(32, 8), 0, stream>>>(wq, wtqkv, 512, 512);
  transpose_w_kernel<<<dim3(16, 16), dim3(32, 8), 0, stream>>>(wk, wtqkv + 262144, 512, 512);
  transpose_w_kernel<<<dim3(16, 16), dim3(32, 8), 0, stream>>>(wv, wtqkv + 524288, 512, 512);
  transpose_w_kernel<<<dim3(16, 16), dim3(32, 8), 0, stream>>>(wo, wot, 512, 512);
  transpose_w_kernel<<<dim3(64, 16), dim3(32, 8), 0, stream>>>(w1, w1t, 512, 2048);
  transpose_w_kernel<<<dim3(16, 64), dim3(32, 8), 0, stream>>>(w2, w2t, 2048, 512);
  projb_kernel<<<80, blk, 0, stream>>>(proj, pb);
  init_mk_kernel<<<1, 64, 0, stream>>>(mk);

  ln_kernel<<<N_SEQ, blk, 0, stream>>>(x, ln1g, ln1b, h_bf);

  gemm_kernel<128, 128, 64, 64, EPI_BF16><<<dim3(64, 4, 3), blk, 0, stream>>>(
      h_bf, 512, 0, wtqkv, 512, 262144, qkv, 512, 4194304, 512,
      nullptr, nullptr, 0, nullptr, 0);

  diag_kernel<<<512, blk, 0, stream>>>(qkv, diag);

  phi_kernel<0><<<dim3(128, 1, 8), blk, 0, stream>>>(qkv, pb, qp, diag, mk);
  phi_kernel<1><<<dim3(128, 1, 8), blk, 0, stream>>>(qkv + 4194304, pb, kp, diag + 65536, mk);
  phi_kernel<2><<<dim3(128, 1, 8), blk, 0, stream>>>(qkv + 4194304, pb, kp, diag + 65536, mk);

  kpsum_part_kernel<<<dim3(32, 8), blk, 0, stream>>>(kp, kps_part);
  kpsum_reduce_kernel<<<10, blk, 0, stream>>>(kps_part, ksum);
  ctx_part_kernel<<<dim3(17, 8, 8), blk, 0, stream>>>(kp, qkv + 8388608, ctx_part);
  ctx_reduce_kernel<<<640, blk, 0, stream>>>(ctx_part, ctxbf);
  dinv_kernel<<<dim3(2048, 8), blk, 0, stream>>>(qp, ksum, dinv);

  gemm_kernel<128, 64, 32, 64, EPI_DINV><<<dim3(64, 1, 8), blk, 0, stream>>>(
      qp, NFP, (long)N_SEQ * NFP, ctxbf, NFP, 64 * NFP, attn, 512, 64, NFP,
      nullptr, nullptr, 0, dinv, N_SEQ);

  gemm_kernel<128, 128, 64, 64, EPI_BIAS_RES_F32><<<dim3(64, 4, 1), blk, 0, stream>>>(
      attn, 512, 0, wot, 512, 0, xb, 512, 0, 512,
      wob, x, 512, nullptr, 0);

  ln_kernel<<<N_SEQ, blk, 0, stream>>>(xb, ln2g, ln2b, h2);

  gemm_kernel<128, 128, 64, 64, EPI_BIAS_GELU><<<dim3(64, 16, 1), blk, 0, stream>>>(
      h2, 512, 0, w1t, 512, 0, gbf, 2048, 0, 512,
      b1, nullptr, 0, nullptr, 0);

  gemm_kernel<128, 128, 64, 64, EPI_BIAS_RES_F32><<<dim3(64, 4, 1), blk, 0, stream>>>(
      gbf, 2048, 0, w2t, 2048, 0, d_out, 512, 0, 2048,
      b2, xb, 512, nullptr, 0);
}

// Round 2
// 288.547 us; speedup vs baseline: 1.9450x; 1.9450x over previous
//
#include <hip/hip_runtime.h>
#include <math.h>

// ---------------------------------------------------------------------------
// Performer encoder layer, MI355X round-1: MFMA-based kp^T v context.
// N=8192, D=512, H=8, DH=64, NF=266 (padded to NFP=320 = 5*64).
// Workspace layout (bytes):
//   0         wtqkv  bf16 [3][512][512]
//   1572864   wot    bf16 [512][512]
//   2097152   w1t    bf16 [2048][512]
//   4194304   w2t    bf16 [512][2048]
//   6291456   projb  bf16 [320][64]
//   6332416   h_bf   bf16 [8192][512]     (reused as attn_bf)
//   14721024  qkv    bf16 [3][8192][512]  (reused as h2_bf)
//   39886848  diag   f32  [2][8][8192]
//   40411136  qp     bf16 [8][8192][320]
//   82354176  kpT    bf16 [8][320][8192]  (transposed feature map of k)
//   124297216 mk     u32  [8]
//   124297472 vT     bf16 [8][64][8192]
//   132686080 part   f32  [8][32][64][320]
//   153657600 ksum   f32  [8][320]
//   153667840 ctxbf  bf16 [8][64][320]
//   153995520 dinv   f32  [8][8192]
//   130468096 gbf    bf16 [8192][2048]    (overlaps vT/part/ksum/ctxbf/dinv,
//                                          lifetimes disjoint: all dead pre-FFN1)
//   total 164022528 B.  xb (f32 [8192][512]) lives in d_out.
// ---------------------------------------------------------------------------

typedef __attribute__((ext_vector_type(8))) short bf16x8;
typedef __attribute__((ext_vector_type(4))) float f32x4;

#define N_SEQ 8192
#define DMODEL 512
#define NHEAD 8
#define DHEAD 64
#define NF 266
#define NFP 320
#define PEPS 1e-4f
#define LNEPS 1e-5f
#define DNORM 0.35355339059327373f
#define RATIO 0.06131393694f

__device__ __forceinline__ unsigned short f2bf(float f) {
  unsigned u = __float_as_uint(f);
  u += 0x7FFFu + ((u >> 16) & 1u);
  return (unsigned short)(u >> 16);
}
__device__ __forceinline__ float bf2f(unsigned short b) {
  return __uint_as_float(((unsigned)b) << 16);
}
__device__ __forceinline__ unsigned enc_f32(float f) {
  unsigned i = __float_as_uint(f);
  return (i & 0x80000000u) ? ~i : (i | 0x80000000u);
}
__device__ __forceinline__ float dec_f32(unsigned u) {
  return (u & 0x80000000u) ? __uint_as_float(u & 0x7FFFFFFFu) : __uint_as_float(~u);
}

// -------------------- small prep kernels --------------------

__global__ void init_mk_kernel(unsigned* mk) {
  if (threadIdx.x < NHEAD) mk[threadIdx.x] = 0x007FFFFFu;  // enc(-inf)
}

// dst[c][r] = bf16(src[r][c]); src is [R][C] f32. grid (C/32, R/32), block (32,8)
__global__ __launch_bounds__(256) void transpose_w_kernel(const float* __restrict__ src,
                                                          unsigned short* __restrict__ dst,
                                                          int R, int C) {
  __shared__ float tile[32][33];
  int c0 = blockIdx.x * 32, r0 = blockIdx.y * 32;
  int tx = threadIdx.x, ty = threadIdx.y;
  #pragma unroll
  for (int i = ty; i < 32; i += 8)
    tile[i][tx] = src[(long)(r0 + i) * C + c0 + tx];
  __syncthreads();
  #pragma unroll
  for (int i = ty; i < 32; i += 8)
    dst[(long)(c0 + i) * R + r0 + tx] = f2bf(tile[tx][i]);
}

__global__ void projb_kernel(const float* __restrict__ proj, unsigned short* __restrict__ pb) {
  int id = blockIdx.x * 256 + threadIdx.x;  // < 320*64
  int j = id >> 6;
  pb[id] = (j < NF) ? f2bf(proj[(long)j * 64 + (id & 63)] * DNORM) : (unsigned short)0;
}

// v [8192][512] (head slice) -> vT [8][64][8192].  grid (1,128,8), block 256.
__global__ __launch_bounds__(256) void vtrans_kernel(const unsigned short* __restrict__ v,
                                                     unsigned short* __restrict__ vT) {
  __shared__ unsigned short tl[64][66];
  int h = blockIdx.z, n0 = blockIdx.y * 64;
  int tid = threadIdx.x;
  int i = tid >> 2, c0 = (tid & 3) * 16;
  const unsigned short* src = v + (long)(n0 + i) * DMODEL + h * DHEAD + c0;
  uint4 u0 = *(const uint4*)src;
  uint4 u1 = *(const uint4*)(src + 8);
  const unsigned short* e0 = (const unsigned short*)&u0;
  const unsigned short* e1 = (const unsigned short*)&u1;
  #pragma unroll
  for (int k = 0; k < 8; ++k) { tl[i][c0 + k] = e0[k]; tl[i][c0 + 8 + k] = e1[k]; }
  __syncthreads();
  unsigned short tmp[16];
  #pragma unroll
  for (int k = 0; k < 16; ++k) tmp[k] = tl[c0 + k][i];
  unsigned short* dst = vT + ((long)h * DHEAD + i) * N_SEQ + n0 + c0;
  *(uint4*)dst = *(uint4*)&tmp[0];
  *(uint4*)(dst + 8) = *(uint4*)&tmp[8];
}

// -------------------- layernorm --------------------

__global__ __launch_bounds__(256) void ln_kernel(const float* __restrict__ x,
                                                 const float* __restrict__ g,
                                                 const float* __restrict__ b,
                                                 unsigned short* __restrict__ out) {
  __shared__ float sred[4];
  int row = blockIdx.x, t = threadIdx.x;
  float2 v = ((const float2*)(x + (long)row * DMODEL))[t];
  float s = v.x + v.y;
  #pragma unroll
  for (int m = 32; m >= 1; m >>= 1) s += __shfl_xor(s, m);
  if ((t & 63) == 0) sred[t >> 6] = s;
  __syncthreads();
  float mu = (sred[0] + sred[1] + sred[2] + sred[3]) * (1.0f / DMODEL);
  __syncthreads();
  float d0 = v.x - mu, d1 = v.y - mu;
  float q = d0 * d0 + d1 * d1;
  #pragma unroll
  for (int m = 32; m >= 1; m >>= 1) q += __shfl_xor(q, m);
  if ((t & 63) == 0) sred[t >> 6] = q;
  __syncthreads();
  float var = (sred[0] + sred[1] + sred[2] + sred[3]) * (1.0f / DMODEL);
  float inv = rsqrtf(var + LNEPS);
  int c = t * 2;
  unsigned short o0 = f2bf(d0 * inv * g[c] + b[c]);
  unsigned short o1 = f2bf(d1 * inv * g[c + 1] + b[c + 1]);
  ((unsigned*)(out + (long)row * DMODEL))[t] = ((unsigned)o1 << 16) | o0;
}

// -------------------- generic bf16 MFMA GEMM --------------------

enum { EPI_BF16 = 0, EPI_DINV = 1, EPI_BIAS_RES_F32 = 2, EPI_BIAS_GELU = 3 };

template <int BM, int BN, int WM, int WN, int EPI>
__global__ __launch_bounds__(256) void gemm_kernel(
    const unsigned short* __restrict__ A, int lda, long sA,
    const unsigned short* __restrict__ Bt, int ldb, long sB,
    void* __restrict__ Cv, int ldc, long sC,
    int K,
    const float* __restrict__ bias,
    const float* __restrict__ res, int ldr,
    const float* __restrict__ dinv, long sDinv) {
  constexpr int BK = 64;
  static_assert((BM / WM) * (BN / WN) == 4, "need 4 waves");
  constexpr int MR = WM / 16, NR = WN / 16;
  constexpr int WNN = BN / WN;
  const int tid = threadIdx.x;
  const int wave = tid >> 6, lane = tid & 63;
  const int lr = lane & 15, lg = lane >> 4;
  const int wr = wave / WNN, wc = wave % WNN;
  const int m0 = blockIdx.x * BM, n0 = blockIdx.y * BN;
  const int z = blockIdx.z;
  A += (long)z * sA;
  Bt += (long)z * sB;

  __shared__ uint4 a_s4[BM * 8];
  __shared__ uint4 b_s4[BN * 8];

  f32x4 acc[MR][NR] = {};

  for (int k0 = 0; k0 < K; k0 += BK) {
    constexpr int AIT = BM * 8 / 256;
    #pragma unroll
    for (int e = 0; e < AIT; ++e) {
      int qq = tid * AIT + e;
      int r = qq >> 3, c = qq & 7;
      a_s4[r * 8 + (c ^ (r & 7))] = *(const uint4*)(A + (long)(m0 + r) * lda + k0 + c * 8);
    }
    constexpr int BIT = BN * 8 / 256;
    #pragma unroll
    for (int e = 0; e < BIT; ++e) {
      int qq = tid * BIT + e;
      int r = qq >> 3, c = qq & 7;
      b_s4[r * 8 + (c ^ (r & 7))] = *(const uint4*)(Bt + (long)(n0 + r) * ldb + k0 + c * 8);
    }
    __syncthreads();
    #pragma unroll
    for (int ks = 0; ks < 2; ++ks) {
      bf16x8 af[MR], bv[NR];
      #pragma unroll
      for (int i = 0; i < MR; ++i) {
        int r = wr * WM + i * 16 + lr;
        af[i] = *(const bf16x8*)&a_s4[r * 8 + ((ks * 4 + lg) ^ (r & 7))];
      }
      #pragma unroll
      for (int j = 0; j < NR; ++j) {
        int r = wc * WN + j * 16 + lr;
        bv[j] = *(const bf16x8*)&b_s4[r * 8 + ((ks * 4 + lg) ^ (r & 7))];
      }
      #pragma unroll
      for (int i = 0; i < MR; ++i)
        #pragma unroll
        for (int j = 0; j < NR; ++j)
          acc[i][j] = __builtin_amdgcn_mfma_f32_16x16x32_bf16(af[i], bv[j], acc[i][j], 0, 0, 0);
    }
    __syncthreads();
  }

  #pragma unroll
  for (int i = 0; i < MR; ++i) {
    #pragma unroll
    for (int j = 0; j < NR; ++j) {
      int gn = n0 + wc * WN + j * 16 + lr;
      #pragma unroll
      for (int rg = 0; rg < 4; ++rg) {
        int gm = m0 + wr * WM + i * 16 + lg * 4 + rg;
        float v = acc[i][j][rg];
        if (EPI == EPI_BF16) {
          ((unsigned short*)Cv)[(long)z * sC + (long)gm * ldc + gn] = f2bf(v);
        } else if (EPI == EPI_DINV) {
          v *= dinv[(long)z * sDinv + gm];
          ((unsigned short*)Cv)[(long)z * sC + (long)gm * ldc + gn] = f2bf(v);
        } else if (EPI == EPI_BIAS_RES_F32) {
          v += bias[gn] + res[(long)gm * ldr + gn];
          ((float*)Cv)[(long)z * sC + (long)gm * ldc + gn] = v;
        } else if (EPI == EPI_BIAS_GELU) {
          v += bias[gn];
          float t3 = 0.7978845608028654f * (v + 0.044715f * v * v * v);
          v = 0.5f * v * (1.0f + tanhf(t3));
          ((unsigned short*)Cv)[(long)z * sC + (long)gm * ldc + gn] = f2bf(v);
        }
      }
    }
  }
}

// -------------------- diag: 0.5*dnorm^2*sum(q^2) --------------------

__global__ __launch_bounds__(256) void diag_kernel(const unsigned short* __restrict__ qkv,
                                                   float* __restrict__ diag) {
  int id = blockIdx.x * 256 + threadIdx.x;  // < 2*8*8192
  int tensor = id >> 16;
  int rem = id & 65535;
  int n = rem >> 3, h = rem & 7;
  const unsigned short* p =
      qkv + (long)tensor * (N_SEQ * DMODEL) + (long)n * DMODEL + h * DHEAD;
  float s = 0.f;
  #pragma unroll
  for (int c = 0; c < 8; ++c) {
    uint4 u = *(const uint4*)(p + c * 8);
    const unsigned short* e = (const unsigned short*)&u;
    #pragma unroll
    for (int i = 0; i < 8; ++i) { float f = bf2f(e[i]); s += f * f; }
  }
  diag[(long)tensor * 65536 + (long)h * N_SEQ + n] = s * 0.0625f;  // *0.5*dnorm^2
}

// -------------------- phi: dd GEMM + epilogue --------------------
// MODE 0: q -> qp row-major [h][n][NFP] (per-row max).
// MODE 1: k max pass (atomicMax enc).
// MODE 2: k exp pass -> kpT [h][NFP][N] (transposed write via LDS).

template <int MODE>
__global__ __launch_bounds__(256) void phi_kernel(
    const unsigned short* __restrict__ QK,  // [8192][512] (q or k base)
    const unsigned short* __restrict__ pb,  // [320][64]
    unsigned short* __restrict__ out,       // qp or kpT
    const float* __restrict__ diag,         // [8][8192]
    unsigned* __restrict__ mk) {
  const int tid = threadIdx.x;
  const int wave = tid >> 6, lane = tid & 63;
  const int lr = lane & 15, lg = lane >> 4;
  const int h = blockIdx.z;
  const int m0 = blockIdx.x * 64;

  __shared__ uint4 smem[3072];       // a(512) + b(2560); reused as kt32 in MODE 2
  __shared__ float sred[4];
  uint4* a_s4 = smem;
  uint4* b_s4 = smem + 512;

  const unsigned short* Aq = QK + (long)m0 * DMODEL + h * DHEAD;

  #pragma unroll
  for (int e = 0; e < 2; ++e) {
    int qq = tid * 2 + e;
    int r = qq >> 3, c = qq & 7;
    a_s4[r * 8 + (c ^ (r & 7))] = *(const uint4*)(Aq + (long)r * DMODEL + c * 8);
  }
  #pragma unroll
  for (int e = 0; e < 10; ++e) {
    int qq = tid * 10 + e;
    int r = qq >> 3, c = qq & 7;
    b_s4[r * 8 + (c ^ (r & 7))] = *(const uint4*)(pb + (long)r * DHEAD + c * 8);
  }
  __syncthreads();

  f32x4 acc[20] = {};
  #pragma unroll
  for (int ks = 0; ks < 2; ++ks) {
    int rA = wave * 16 + lr;
    bf16x8 af = *(const bf16x8*)&a_s4[rA * 8 + ((ks * 4 + lg) ^ (rA & 7))];
    #pragma unroll
    for (int j = 0; j < 20; ++j) {
      int rB = j * 16 + lr;
      bf16x8 bv = *(const bf16x8*)&b_s4[rB * 8 + ((ks * 4 + lg) ^ (rB & 7))];
      acc[j] = __builtin_amdgcn_mfma_f32_16x16x32_bf16(af, bv, acc[j], 0, 0, 0);
    }
  }

  const int gmb = m0 + wave * 16 + lg * 4;  // + rg

  if (MODE == 1) {
    float m = -3.0e38f;
    #pragma unroll
    for (int j = 0; j < 17; ++j) {
      bool valid = (j < 16) || (lr < 10);  // col = j*16+lr < 266
      if (valid) {
        #pragma unroll
        for (int rg = 0; rg < 4; ++rg) m = fmaxf(m, acc[j][rg]);
      }
    }
    #pragma unroll
    for (int s = 1; s < 64; s <<= 1) m = fmaxf(m, __shfl_xor(m, s));
    if (lane == 0) sred[wave] = m;
    __syncthreads();
    if (tid == 0) {
      float mm = fmaxf(fmaxf(sred[0], sred[1]), fmaxf(sred[2], sred[3]));
      atomicMax(&mk[h], enc_f32(mm));
    }
    return;
  }

  float dg[4];
  #pragma unroll
  for (int rg = 0; rg < 4; ++rg) dg[rg] = diag[(long)h * N_SEQ + gmb + rg];

  if (MODE == 0) {
    float mrow[4];
    #pragma unroll
    for (int rg = 0; rg < 4; ++rg) mrow[rg] = -3.0e38f;
    #pragma unroll
    for (int j = 0; j < 17; ++j) {
      bool valid = (j < 16) || (lr < 10);
      if (valid) {
        #pragma unroll
        for (int rg = 0; rg < 4; ++rg) mrow[rg] = fmaxf(mrow[rg], acc[j][rg]);
      }
    }
    #pragma unroll
    for (int s = 1; s < 16; s <<= 1)
      #pragma unroll
      for (int rg = 0; rg < 4; ++rg) mrow[rg] = fmaxf(mrow[rg], __shfl_xor(mrow[rg], s));

    #pragma unroll
    for (int j = 0; j < 20; ++j) {
      int col = j * 16 + lr;
      #pragma unroll
      for (int rg = 0; rg < 4; ++rg) {
        float v = 0.f;
        if (col < NF) v = RATIO * (expf(acc[j][rg] - dg[rg] - mrow[rg]) + PEPS);
        out[((long)h * N_SEQ + gmb + rg) * NFP + col] = f2bf(v);
      }
    }
  } else {
    // MODE 2: exp with global max, transposed write kpT[h][col][n]
    float mh = dec_f32(mk[h]);
    unsigned* kt32 = (unsigned*)smem;  // [320][33] uints (pairs of bf16 along n)
    __syncthreads();                   // a_s4/b_s4 reads done
    #pragma unroll
    for (int j = 0; j < 20; ++j) {
      int col = j * 16 + lr;
      #pragma unroll
      for (int p = 0; p < 2; ++p) {
        float v0 = 0.f, v1 = 0.f;
        if (col < NF) {
          v0 = RATIO * (expf(acc[j][2 * p] - dg[2 * p] - mh) + PEPS);
          v1 = RATIO * (expf(acc[j][2 * p + 1] - dg[2 * p + 1] - mh) + PEPS);
        }
        kt32[col * 33 + wave * 8 + lg * 2 + p] =
            (unsigned)f2bf(v0) | ((unsigned)f2bf(v1) << 16);
      }
    }
    __syncthreads();
    #pragma unroll
    for (int it = 0; it < 10; ++it) {
      int r = it * 32 + (tid >> 3);
      int cu = (tid & 7) * 4;
      uint4 o;
      o.x = kt32[r * 33 + cu + 0];
      o.y = kt32[r * 33 + cu + 1];
      o.z = kt32[r * 33 + cu + 2];
      o.w = kt32[r * 33 + cu + 3];
      *(uint4*)(out + ((long)h * NFP + r) * N_SEQ + m0 + cu * 2) = o;
    }
  }
}

// -------------------- ksum[h][j] = sum_n kpT[h][j][n] --------------------
// grid (80, 8), block 256 (4 waves, one j-row per wave)

__global__ __launch_bounds__(256) void ksum_kernel(const unsigned short* __restrict__ kpT,
                                                   float* __restrict__ ksum) {
  int h = blockIdx.y;
  int j = blockIdx.x * 4 + (threadIdx.x >> 6);
  int lane = threadIdx.x & 63;
  const unsigned short* row = kpT + ((long)h * NFP + j) * N_SEQ;
  float s = 0.f;
  #pragma unroll 4
  for (int it = 0; it < 16; ++it) {
    uint4 u = *(const uint4*)(row + (it * 64 + lane) * 8);
    const unsigned short* e = (const unsigned short*)&u;
    #pragma unroll
    for (int i = 0; i < 8; ++i) s += bf2f(e[i]);
  }
  #pragma unroll
  for (int m = 32; m >= 1; m >>= 1) s += __shfl_xor(s, m);
  if (lane == 0) ksum[h * NFP + j] = s;
}

// -------------------- ctx split-K MFMA: part[h][kc] = vT chunk x kpT chunk ----
// grid (32 kc, 8 h), block 256. C[64 d][320 j], K-chunk = 256.

__global__ __launch_bounds__(256) void ctx_mfma_kernel(
    const unsigned short* __restrict__ vT,   // [8][64][8192]
    const unsigned short* __restrict__ kpT,  // [8][320][8192]
    float* __restrict__ part) {              // [8][32][64][320]
  const int tid = threadIdx.x;
  const int wave = tid >> 6, lane = tid & 63;
  const int lr = lane & 15, lg = lane >> 4;
  const int wr = wave >> 1, wc = wave & 1;  // WM=32, WN=160
  const int kc = blockIdx.x, h = blockIdx.y;

  __shared__ uint4 a_s4[64 * 8];
  __shared__ uint4 b_s4[NFP * 8];

  const unsigned short* A = vT + (long)h * DHEAD * N_SEQ + kc * 256;
  const unsigned short* B = kpT + (long)h * NFP * N_SEQ + kc * 256;

  f32x4 acc[2][10] = {};

  for (int k0 = 0; k0 < 256; k0 += 64) {
    #pragma unroll
    for (int e = 0; e < 2; ++e) {
      int qq = tid * 2 + e;
      int r = qq >> 3, c = qq & 7;
      a_s4[r * 8 + (c ^ (r & 7))] = *(const uint4*)(A + (long)r * N_SEQ + k0 + c * 8);
    }
    #pragma unroll
    for (int e = 0; e < 10; ++e) {
      int qq = tid * 10 + e;
      int r = qq >> 3, c = qq & 7;
      b_s4[r * 8 + (c ^ (r & 7))] = *(const uint4*)(B + (long)r * N_SEQ + k0 + c * 8);
    }
    __syncthreads();
    #pragma unroll
    for (int ks = 0; ks < 2; ++ks) {
      bf16x8 af[2], bv[10];
      #pragma unroll
      for (int i = 0; i < 2; ++i) {
        int r = wr * 32 + i * 16 + lr;
        af[i] = *(const bf16x8*)&a_s4[r * 8 + ((ks * 4 + lg) ^ (r & 7))];
      }
      #pragma unroll
      for (int j = 0; j < 10; ++j) {
        int r = wc * 160 + j * 16 + lr;
        bv[j] = *(const bf16x8*)&b_s4[r * 8 + ((ks * 4 + lg) ^ (r & 7))];
      }
      #pragma unroll
      for (int i = 0; i < 2; ++i)
        #pragma unroll
        for (int j = 0; j < 10; ++j)
          acc[i][j] = __builtin_amdgcn_mfma_f32_16x16x32_bf16(af[i], bv[j], acc[i][j], 0, 0, 0);
    }
    __syncthreads();
  }

  float* pbase = part + ((long)(h * 32 + kc)) * 64 * NFP;
  #pragma unroll
  for (int i = 0; i < 2; ++i) {
    #pragma unroll
    for (int j = 0; j < 10; ++j) {
      int gn = wc * 160 + j * 16 + lr;
      #pragma unroll
      for (int rg = 0; rg < 4; ++rg) {
        int gm = wr * 32 + i * 16 + lg * 4 + rg;
        pbase[(long)gm * NFP + gn] = acc[i][j][rg];
      }
    }
  }
}

__global__ void ctx_reduce_kernel(const float* __restrict__ part,
                                  unsigned short* __restrict__ ctxbf) {
  int i = blockIdx.x * 256 + threadIdx.x;  // < 8*64*320
  int h = i / (64 * NFP);
  int rem = i % (64 * NFP);
  float s = 0.f;
  #pragma unroll 4
  for (int kc = 0; kc < 32; ++kc)
    s += part[((long)(h * 32 + kc)) * 64 * NFP + rem];
  ctxbf[i] = f2bf(s);
}

// -------------------- d_inv = 1 / (qp . ksum) --------------------

__global__ __launch_bounds__(256) void dinv_kernel(const unsigned short* __restrict__ qp,
                                                   const float* __restrict__ ksum,
                                                   float* __restrict__ dinv) {
  __shared__ float ks[NFP];
  int h = blockIdx.y, t = threadIdx.x;
  ks[t] = ksum[h * NFP + t];
  if (t < NFP - 256) ks[256 + t] = ksum[h * NFP + 256 + t];
  __syncthreads();
  int wave = t >> 6, lane = t & 63;
  int n = blockIdx.x * 4 + wave;
  const unsigned short* row = qp + ((long)h * N_SEQ + n) * NFP;
  float s = 0.f;
  {
    uint2 u = ((const uint2*)row)[lane];
    s += bf2f((unsigned short)(u.x & 0xFFFF)) * ks[lane * 4 + 0];
    s += bf2f((unsigned short)(u.x >> 16)) * ks[lane * 4 + 1];
    s += bf2f((unsigned short)(u.y & 0xFFFF)) * ks[lane * 4 + 2];
    s += bf2f((unsigned short)(u.y >> 16)) * ks[lane * 4 + 3];
  }
  if (lane < 4) {
    uint2 u = ((const uint2*)row)[64 + lane];
    int jb = 256 + lane * 4;
    s += bf2f((unsigned short)(u.x & 0xFFFF)) * ks[jb + 0];
    s += bf2f((unsigned short)(u.x >> 16)) * ks[jb + 1];
    s += bf2f((unsigned short)(u.y & 0xFFFF)) * ks[jb + 2];
    s += bf2f((unsigned short)(u.y >> 16)) * ks[jb + 3];
  }
  #pragma unroll
  for (int m = 32; m >= 1; m >>= 1) s += __shfl_xor(s, m);
  if (lane == 0) dinv[(long)h * N_SEQ + n] = 1.0f / s;
}

// -------------------- launch --------------------

extern "C" void kernel_launch(void* const* d_in, const int* in_sizes, int n_in,
                              void* d_out, int out_size, void* d_ws, size_t ws_size,
                              hipStream_t stream) {
  const float* x    = (const float*)d_in[0];
  const float* proj = (const float*)d_in[1];
  const float* ln1g = (const float*)d_in[2];
  const float* ln1b = (const float*)d_in[3];
  const float* wq   = (const float*)d_in[4];
  const float* wk   = (const float*)d_in[5];
  const float* wv   = (const float*)d_in[6];
  const float* wo   = (const float*)d_in[7];
  const float* wob  = (const float*)d_in[8];
  const float* ln2g = (const float*)d_in[9];
  const float* ln2b = (const float*)d_in[10];
  const float* w1   = (const float*)d_in[11];
  const float* b1   = (const float*)d_in[12];
  const float* w2   = (const float*)d_in[13];
  const float* b2   = (const float*)d_in[14];

  char* ws = (char*)d_ws;
  unsigned short* wtqkv = (unsigned short*)(ws + 0);
  unsigned short* wot   = (unsigned short*)(ws + 1572864);
  unsigned short* w1t   = (unsigned short*)(ws + 2097152);
  unsigned short* w2t   = (unsigned short*)(ws + 4194304);
  unsigned short* pb    = (unsigned short*)(ws + 6291456);
  unsigned short* h_bf  = (unsigned short*)(ws + 6332416);
  unsigned short* qkv   = (unsigned short*)(ws + 14721024);
  float* diag           = (float*)(ws + 39886848);
  unsigned short* qp    = (unsigned short*)(ws + 40411136);
  unsigned short* kpT   = (unsigned short*)(ws + 82354176);
  unsigned* mk          = (unsigned*)(ws + 124297216);
  unsigned short* vT    = (unsigned short*)(ws + 124297472);
  float* part           = (float*)(ws + 132686080);
  float* ksum           = (float*)(ws + 153657600);
  unsigned short* ctxbf = (unsigned short*)(ws + 153667840);
  float* dinv           = (float*)(ws + 153995520);
  unsigned short* gbf   = (unsigned short*)(ws + 130468096);
  unsigned short* attn  = h_bf;  // reuse (h_bf dead after QKV GEMM)
  unsigned short* h2    = qkv;   // reuse (qkv dead after phi/vtrans)
  float* xb             = (float*)d_out;

  dim3 blk(256);

  transpose_w_kernel<<<dim3(16, 16), dim3(32, 8), 0, stream>>>(wq, wtqkv, 512, 512);
  transpose_w_kernel<<<dim3(16, 16), dim3(32, 8), 0, stream>>>(wk, wtqkv + 262144, 512, 512);
  transpose_w_kernel<<<dim3(16, 16), dim3(32, 8), 0, stream>>>(wv, wtqkv + 524288, 512, 512);
  transpose_w_kernel<<<dim3(16, 16), dim3(32, 8), 0, stream>>>(wo, wot, 512, 512);
  transpose_w_kernel<<<dim3(64, 16), dim3(32, 8), 0, stream>>>(w1, w1t, 512, 2048);
  transpose_w_kernel<<<dim3(16, 64), dim3(32, 8), 0, stream>>>(w2, w2t, 2048, 512);
  projb_kernel<<<80, blk, 0, stream>>>(proj, pb);
  init_mk_kernel<<<1, 64, 0, stream>>>(mk);

  ln_kernel<<<N_SEQ, blk, 0, stream>>>(x, ln1g, ln1b, h_bf);

  gemm_kernel<128, 128, 64, 64, EPI_BF16><<<dim3(64, 4, 3), blk, 0, stream>>>(
      h_bf, 512, 0, wtqkv, 512, 262144, qkv, 512, 4194304, 512,
      nullptr, nullptr, 0, nullptr, 0);

  diag_kernel<<<512, blk, 0, stream>>>(qkv, diag);
  vtrans_kernel<<<dim3(1, 128, 8), blk, 0, stream>>>(qkv + 8388608, vT);

  phi_kernel<0><<<dim3(128, 1, 8), blk, 0, stream>>>(qkv, pb, qp, diag, mk);
  phi_kernel<1><<<dim3(128, 1, 8), blk, 0, stream>>>(qkv + 4194304, pb, kpT, diag + 65536, mk);
  phi_kernel<2><<<dim3(128, 1, 8), blk, 0, stream>>>(qkv + 4194304, pb, kpT, diag + 65536, mk);

  ksum_kernel<<<dim3(80, 8), blk, 0, stream>>>(kpT, ksum);
  ctx_mfma_kernel<<<dim3(32, 8), blk, 0, stream>>>(vT, kpT, part);
  ctx_reduce_kernel<<<640, blk, 0, stream>>>(part, ctxbf);
  dinv_kernel<<<dim3(2048, 8), blk, 0, stream>>>(qp, ksum, dinv);

  gemm_kernel<128, 64, 32, 64, EPI_DINV><<<dim3(64, 1, 8), blk, 0, stream>>>(
      qp, NFP, (long)N_SEQ * NFP, ctxbf, NFP, 64 * NFP, attn, 512, 64, NFP,
      nullptr, nullptr, 0, dinv, N_SEQ);

  gemm_kernel<128, 128, 64, 64, EPI_BIAS_RES_F32><<<dim3(64, 4, 1), blk, 0, stream>>>(
      attn, 512, 0, wot, 512, 0, xb, 512, 0, 512,
      wob, x, 512, nullptr, 0);

  ln_kernel<<<N_SEQ, blk, 0, stream>>>(xb, ln2g, ln2b, h2);

  gemm_kernel<128, 128, 64, 64, EPI_BIAS_GELU><<<dim3(64, 16, 1), blk, 0, stream>>>(
      h2, 512, 0, w1t, 512, 0, gbf, 2048, 0, 512,
      b1, nullptr, 0, nullptr, 0);

  gemm_kernel<128, 128, 64, 64, EPI_BIAS_RES_F32><<<dim3(64, 4, 1), blk, 0, stream>>>(
      gbf, 2048, 0, w2t, 2048, 0, d_out, 512, 0, 2048,
      b2, xb, 512, nullptr, 0);
}

// Round 3
// 252.521 us; speedup vs baseline: 2.2225x; 1.1427x over previous
//
#include <hip/hip_runtime.h>
#include <math.h>

// ---------------------------------------------------------------------------
// Performer encoder layer, MI355X round-2: global_load_lds staging everywhere
// (linear LDS dest + inverse-swizzled global source, swizzled ds_read), and
// dinv fused into the attn GEMM via a ksum column (col 64 of padded ctx).
// N=8192, D=512, H=8, DH=64, NF=266 (padded to NFP=320 = 5*64).
// Workspace layout (bytes):
//   0         wtqkv  bf16 [3][512][512]
//   1572864   wot    bf16 [512][512]
//   2097152   w1t    bf16 [2048][512]
//   4194304   w2t    bf16 [512][2048]
//   6291456   projb  bf16 [320][64]
//   6332416   h_bf   bf16 [8192][512]     (reused as attn_bf)
//   14721024  qkv    bf16 [3][8192][512]  (reused as h2_bf)
//   39886848  diag   f32  [2][8][8192]
//   40411136  qp     bf16 [8][8192][320]
//   82354176  kpT    bf16 [8][320][8192]
//   124297216 mk     u32  [8]
//   124297472 vT     bf16 [8][64][8192]
//   132686080 part   f32  [8][32][64][320]
//   153657600 ksum   f32  [8][320]
//   153667840 ctxpad bf16 [8][96][320]   (rows 0-63 ctx^T, row 64 ksum, 65+ zero)
//   130468096 gbf    bf16 [8192][2048]   (overlaps vT/part/ksum/ctxpad;
//                                         lifetimes disjoint: all dead pre-FFN1)
//   total 164022528 B.  xb (f32 [8192][512]) lives in d_out.
// ---------------------------------------------------------------------------

typedef __attribute__((ext_vector_type(8))) short bf16x8;
typedef __attribute__((ext_vector_type(4))) float f32x4;

#define N_SEQ 8192
#define DMODEL 512
#define NHEAD 8
#define DHEAD 64
#define NF 266
#define NFP 320
#define PEPS 1e-4f
#define LNEPS 1e-5f
#define DNORM 0.35355339059327373f
#define RATIO 0.06131393694f

__device__ __forceinline__ unsigned short f2bf(float f) {
  unsigned u = __float_as_uint(f);
  u += 0x7FFFu + ((u >> 16) & 1u);
  return (unsigned short)(u >> 16);
}
__device__ __forceinline__ float bf2f(unsigned short b) {
  return __uint_as_float(((unsigned)b) << 16);
}
__device__ __forceinline__ unsigned enc_f32(float f) {
  unsigned i = __float_as_uint(f);
  return (i & 0x80000000u) ? ~i : (i | 0x80000000u);
}
__device__ __forceinline__ float dec_f32(unsigned u) {
  return (u & 0x80000000u) ? __uint_as_float(u & 0x7FFFFFFFu) : __uint_as_float(~u);
}

// async global->LDS, 16B per lane. LDS dest must be wave-uniform base; HW adds
// lane*16. Global source is per-lane (pre-swizzled by caller).
__device__ __forceinline__ void g2l16(const void* g, void* l) {
  __builtin_amdgcn_global_load_lds(
      (const __attribute__((address_space(1))) void*)g,
      (__attribute__((address_space(3))) void*)l, 16, 0, 0);
}

// -------------------- small prep kernels --------------------

__global__ void init_mk_kernel(unsigned* mk) {
  if (threadIdx.x < NHEAD) mk[threadIdx.x] = 0x007FFFFFu;  // enc(-inf)
}

// dst[c][r] = bf16(src[r][c]); src is [R][C] f32. grid (C/32, R/32), block (32,8)
__global__ __launch_bounds__(256) void transpose_w_kernel(const float* __restrict__ src,
                                                          unsigned short* __restrict__ dst,
                                                          int R, int C) {
  __shared__ float tile[32][33];
  int c0 = blockIdx.x * 32, r0 = blockIdx.y * 32;
  int tx = threadIdx.x, ty = threadIdx.y;
  #pragma unroll
  for (int i = ty; i < 32; i += 8)
    tile[i][tx] = src[(long)(r0 + i) * C + c0 + tx];
  __syncthreads();
  #pragma unroll
  for (int i = ty; i < 32; i += 8)
    dst[(long)(c0 + i) * R + r0 + tx] = f2bf(tile[tx][i]);
}

__global__ void projb_kernel(const float* __restrict__ proj, unsigned short* __restrict__ pb) {
  int id = blockIdx.x * 256 + threadIdx.x;  // < 320*64
  int j = id >> 6;
  pb[id] = (j < NF) ? f2bf(proj[(long)j * 64 + (id & 63)] * DNORM) : (unsigned short)0;
}

// v [8192][512] (head slice) -> vT [8][64][8192].  grid (1,128,8), block 256.
__global__ __launch_bounds__(256) void vtrans_kernel(const unsigned short* __restrict__ v,
                                                     unsigned short* __restrict__ vT) {
  __shared__ unsigned short tl[64][66];
  int h = blockIdx.z, n0 = blockIdx.y * 64;
  int tid = threadIdx.x;
  int i = tid >> 2, c0 = (tid & 3) * 16;
  const unsigned short* src = v + (long)(n0 + i) * DMODEL + h * DHEAD + c0;
  uint4 u0 = *(const uint4*)src;
  uint4 u1 = *(const uint4*)(src + 8);
  const unsigned short* e0 = (const unsigned short*)&u0;
  const unsigned short* e1 = (const unsigned short*)&u1;
  #pragma unroll
  for (int k = 0; k < 8; ++k) { tl[i][c0 + k] = e0[k]; tl[i][c0 + 8 + k] = e1[k]; }
  __syncthreads();
  unsigned short tmp[16];
  #pragma unroll
  for (int k = 0; k < 16; ++k) tmp[k] = tl[c0 + k][i];
  unsigned short* dst = vT + ((long)h * DHEAD + i) * N_SEQ + n0 + c0;
  *(uint4*)dst = *(uint4*)&tmp[0];
  *(uint4*)(dst + 8) = *(uint4*)&tmp[8];
}

// -------------------- layernorm --------------------

__global__ __launch_bounds__(256) void ln_kernel(const float* __restrict__ x,
                                                 const float* __restrict__ g,
                                                 const float* __restrict__ b,
                                                 unsigned short* __restrict__ out) {
  __shared__ float sred[4];
  int row = blockIdx.x, t = threadIdx.x;
  float2 v = ((const float2*)(x + (long)row * DMODEL))[t];
  float s = v.x + v.y;
  #pragma unroll
  for (int m = 32; m >= 1; m >>= 1) s += __shfl_xor(s, m);
  if ((t & 63) == 0) sred[t >> 6] = s;
  __syncthreads();
  float mu = (sred[0] + sred[1] + sred[2] + sred[3]) * (1.0f / DMODEL);
  __syncthreads();
  float d0 = v.x - mu, d1 = v.y - mu;
  float q = d0 * d0 + d1 * d1;
  #pragma unroll
  for (int m = 32; m >= 1; m >>= 1) q += __shfl_xor(q, m);
  if ((t & 63) == 0) sred[t >> 6] = q;
  __syncthreads();
  float var = (sred[0] + sred[1] + sred[2] + sred[3]) * (1.0f / DMODEL);
  float inv = rsqrtf(var + LNEPS);
  int c = t * 2;
  unsigned short o0 = f2bf(d0 * inv * g[c] + b[c]);
  unsigned short o1 = f2bf(d1 * inv * g[c + 1] + b[c + 1]);
  ((unsigned*)(out + (long)row * DMODEL))[t] = ((unsigned)o1 << 16) | o0;
}

// -------------------- generic bf16 MFMA GEMM --------------------
// C[M,N] = A[M,K] x Bt[N,K]^T, fp32 acc. 256 threads = 4 waves. BK=64.
// Staging: global_load_lds_dwordx4, linear LDS dest, source column pre-XORed
// (c ^ (r&7)) so the swizzled ds_read yields the un-permuted fragment.
// EPI_CTX: Bt has 96 rows (64 ctx + ksum row at 64 + zeros); epilogue divides
// cols 0..63 by the col-64 dot product (d = qp . ksum), broadcast via shfl.

enum { EPI_BF16 = 0, EPI_CTX = 1, EPI_BIAS_RES_F32 = 2, EPI_BIAS_GELU = 3 };

template <int BM, int BN, int WM, int WN, int EPI>
__global__ __launch_bounds__(256) void gemm_kernel(
    const unsigned short* __restrict__ A, int lda, long sA,
    const unsigned short* __restrict__ Bt, int ldb, long sB,
    void* __restrict__ Cv, int ldc, long sC,
    int K,
    const float* __restrict__ bias,
    const float* __restrict__ res, int ldr) {
  constexpr int BK = 64;
  static_assert((BM / WM) * (BN / WN) == 4, "need 4 waves");
  constexpr int MR = WM / 16, NR = WN / 16;
  constexpr int WNN = BN / WN;
  constexpr int AIT = BM * 8 / 256;
  constexpr int BIT = BN * 8 / 256;
  const int tid = threadIdx.x;
  const int wave = tid >> 6, lane = tid & 63;
  const int lr = lane & 15, lg = lane >> 4;
  const int wr = wave / WNN, wc = wave % WNN;
  const int m0 = blockIdx.x * BM, n0 = blockIdx.y * BN;
  const int z = blockIdx.z;
  A += (long)z * sA;
  Bt += (long)z * sB;

  __shared__ uint4 a_s4[BM * 8];
  __shared__ uint4 b_s4[BN * 8];

  // per-thread pre-swizzled global sources (k0-invariant part)
  const unsigned short* asrc[AIT];
  #pragma unroll
  for (int e = 0; e < AIT; ++e) {
    int chunk = e * 256 + tid;
    int r = chunk >> 3, c = chunk & 7;
    asrc[e] = A + (long)(m0 + r) * lda + (c ^ (r & 7)) * 8;
  }
  const unsigned short* bsrc[BIT];
  #pragma unroll
  for (int e = 0; e < BIT; ++e) {
    int chunk = e * 256 + tid;
    int r = chunk >> 3, c = chunk & 7;
    bsrc[e] = Bt + (long)(n0 + r) * ldb + (c ^ (r & 7)) * 8;
  }
  const int wbase = tid & 192;  // wave-uniform chunk base within a 256-chunk issue

  f32x4 acc[MR][NR] = {};

  for (int k0 = 0; k0 < K; k0 += BK) {
    #pragma unroll
    for (int e = 0; e < AIT; ++e)
      g2l16(asrc[e] + k0, a_s4 + e * 256 + wbase);
    #pragma unroll
    for (int e = 0; e < BIT; ++e)
      g2l16(bsrc[e] + k0, b_s4 + e * 256 + wbase);
    __syncthreads();
    #pragma unroll
    for (int ks = 0; ks < 2; ++ks) {
      bf16x8 af[MR], bv[NR];
      #pragma unroll
      for (int i = 0; i < MR; ++i) {
        int r = wr * WM + i * 16 + lr;
        af[i] = *(const bf16x8*)&a_s4[r * 8 + ((ks * 4 + lg) ^ (r & 7))];
      }
      #pragma unroll
      for (int j = 0; j < NR; ++j) {
        int r = wc * WN + j * 16 + lr;
        bv[j] = *(const bf16x8*)&b_s4[r * 8 + ((ks * 4 + lg) ^ (r & 7))];
      }
      #pragma unroll
      for (int i = 0; i < MR; ++i)
        #pragma unroll
        for (int j = 0; j < NR; ++j)
          acc[i][j] = __builtin_amdgcn_mfma_f32_16x16x32_bf16(af[i], bv[j], acc[i][j], 0, 0, 0);
    }
    __syncthreads();
  }

  if constexpr (EPI == EPI_CTX) {
    #pragma unroll
    for (int i = 0; i < MR; ++i) {
      #pragma unroll
      for (int rg = 0; rg < 4; ++rg) {
        float dv = __shfl(acc[i][4][rg], lane & 48);  // col 64 (lr==0 lane)
        float inv = 1.0f / dv;
        int gm = m0 + wr * WM + i * 16 + lg * 4 + rg;
        #pragma unroll
        for (int j = 0; j < 4; ++j) {
          int gn = j * 16 + lr;  // cols 0..63
          ((unsigned short*)Cv)[(long)z * sC + (long)gm * ldc + gn] =
              f2bf(acc[i][j][rg] * inv);
        }
      }
    }
    return;
  }

  #pragma unroll
  for (int i = 0; i < MR; ++i) {
    #pragma unroll
    for (int j = 0; j < NR; ++j) {
      int gn = n0 + wc * WN + j * 16 + lr;
      #pragma unroll
      for (int rg = 0; rg < 4; ++rg) {
        int gm = m0 + wr * WM + i * 16 + lg * 4 + rg;
        float v = acc[i][j][rg];
        if (EPI == EPI_BF16) {
          ((unsigned short*)Cv)[(long)z * sC + (long)gm * ldc + gn] = f2bf(v);
        } else if (EPI == EPI_BIAS_RES_F32) {
          v += bias[gn] + res[(long)gm * ldr + gn];
          ((float*)Cv)[(long)z * sC + (long)gm * ldc + gn] = v;
        } else if (EPI == EPI_BIAS_GELU) {
          v += bias[gn];
          float t3 = 0.7978845608028654f * (v + 0.044715f * v * v * v);
          v = 0.5f * v * (1.0f + tanhf(t3));
          ((unsigned short*)Cv)[(long)z * sC + (long)gm * ldc + gn] = f2bf(v);
        }
      }
    }
  }
}

// -------------------- diag: 0.5*dnorm^2*sum(q^2) --------------------

__global__ __launch_bounds__(256) void diag_kernel(const unsigned short* __restrict__ qkv,
                                                   float* __restrict__ diag) {
  int id = blockIdx.x * 256 + threadIdx.x;  // < 2*8*8192
  int tensor = id >> 16;
  int rem = id & 65535;
  int n = rem >> 3, h = rem & 7;
  const unsigned short* p =
      qkv + (long)tensor * (N_SEQ * DMODEL) + (long)n * DMODEL + h * DHEAD;
  float s = 0.f;
  #pragma unroll
  for (int c = 0; c < 8; ++c) {
    uint4 u = *(const uint4*)(p + c * 8);
    const unsigned short* e = (const unsigned short*)&u;
    #pragma unroll
    for (int i = 0; i < 8; ++i) { float f = bf2f(e[i]); s += f * f; }
  }
  diag[(long)tensor * 65536 + (long)h * N_SEQ + n] = s * 0.0625f;  // *0.5*dnorm^2
}

// -------------------- phi: dd GEMM + epilogue --------------------
// MODE 0: q -> qp row-major [h][n][NFP] (per-row max).
// MODE 1: k max pass (atomicMax enc).
// MODE 2: k exp pass -> kpT [h][NFP][N] (transposed write via LDS).

template <int MODE>
__global__ __launch_bounds__(256) void phi_kernel(
    const unsigned short* __restrict__ QK,  // [8192][512] (q or k base)
    const unsigned short* __restrict__ pb,  // [320][64]
    unsigned short* __restrict__ out,       // qp or kpT
    const float* __restrict__ diag,         // [8][8192]
    unsigned* __restrict__ mk) {
  const int tid = threadIdx.x;
  const int wave = tid >> 6, lane = tid & 63;
  const int lr = lane & 15, lg = lane >> 4;
  const int h = blockIdx.z;
  const int m0 = blockIdx.x * 64;

  __shared__ uint4 smem[3072];       // a(512) + b(2560); reused as kt32 in MODE 2
  __shared__ float sred[4];
  uint4* a_s4 = smem;
  uint4* b_s4 = smem + 512;

  const unsigned short* Aq = QK + (long)m0 * DMODEL + h * DHEAD;
  const int wbase = tid & 192;

  #pragma unroll
  for (int e = 0; e < 2; ++e) {
    int chunk = e * 256 + tid;
    int r = chunk >> 3, c = chunk & 7;
    g2l16(Aq + (long)r * DMODEL + (c ^ (r & 7)) * 8, a_s4 + e * 256 + wbase);
  }
  #pragma unroll
  for (int e = 0; e < 10; ++e) {
    int chunk = e * 256 + tid;
    int r = chunk >> 3, c = chunk & 7;
    g2l16(pb + (long)r * DHEAD + (c ^ (r & 7)) * 8, b_s4 + e * 256 + wbase);
  }
  __syncthreads();

  f32x4 acc[20] = {};
  #pragma unroll
  for (int ks = 0; ks < 2; ++ks) {
    int rA = wave * 16 + lr;
    bf16x8 af = *(const bf16x8*)&a_s4[rA * 8 + ((ks * 4 + lg) ^ (rA & 7))];
    #pragma unroll
    for (int j = 0; j < 20; ++j) {
      int rB = j * 16 + lr;
      bf16x8 bv = *(const bf16x8*)&b_s4[rB * 8 + ((ks * 4 + lg) ^ (rB & 7))];
      acc[j] = __builtin_amdgcn_mfma_f32_16x16x32_bf16(af, bv, acc[j], 0, 0, 0);
    }
  }

  const int gmb = m0 + wave * 16 + lg * 4;  // + rg

  if (MODE == 1) {
    float m = -3.0e38f;
    #pragma unroll
    for (int j = 0; j < 17; ++j) {
      bool valid = (j < 16) || (lr < 10);  // col = j*16+lr < 266
      if (valid) {
        #pragma unroll
        for (int rg = 0; rg < 4; ++rg) m = fmaxf(m, acc[j][rg]);
      }
    }
    #pragma unroll
    for (int s = 1; s < 64; s <<= 1) m = fmaxf(m, __shfl_xor(m, s));
    if (lane == 0) sred[wave] = m;
    __syncthreads();
    if (tid == 0) {
      float mm = fmaxf(fmaxf(sred[0], sred[1]), fmaxf(sred[2], sred[3]));
      atomicMax(&mk[h], enc_f32(mm));
    }
    return;
  }

  float dg[4];
  #pragma unroll
  for (int rg = 0; rg < 4; ++rg) dg[rg] = diag[(long)h * N_SEQ + gmb + rg];

  if (MODE == 0) {
    float mrow[4];
    #pragma unroll
    for (int rg = 0; rg < 4; ++rg) mrow[rg] = -3.0e38f;
    #pragma unroll
    for (int j = 0; j < 17; ++j) {
      bool valid = (j < 16) || (lr < 10);
      if (valid) {
        #pragma unroll
        for (int rg = 0; rg < 4; ++rg) mrow[rg] = fmaxf(mrow[rg], acc[j][rg]);
      }
    }
    #pragma unroll
    for (int s = 1; s < 16; s <<= 1)
      #pragma unroll
      for (int rg = 0; rg < 4; ++rg) mrow[rg] = fmaxf(mrow[rg], __shfl_xor(mrow[rg], s));

    #pragma unroll
    for (int j = 0; j < 20; ++j) {
      int col = j * 16 + lr;
      #pragma unroll
      for (int rg = 0; rg < 4; ++rg) {
        float v = 0.f;
        if (col < NF) v = RATIO * (expf(acc[j][rg] - dg[rg] - mrow[rg]) + PEPS);
        out[((long)h * N_SEQ + gmb + rg) * NFP + col] = f2bf(v);
      }
    }
  } else {
    // MODE 2: exp with global max, transposed write kpT[h][col][n]
    float mh = dec_f32(mk[h]);
    unsigned* kt32 = (unsigned*)smem;  // [320][33] uints (pairs of bf16 along n)
    __syncthreads();                   // a_s4/b_s4 reads done
    #pragma unroll
    for (int j = 0; j < 20; ++j) {
      int col = j * 16 + lr;
      #pragma unroll
      for (int p = 0; p < 2; ++p) {
        float v0 = 0.f, v1 = 0.f;
        if (col < NF) {
          v0 = RATIO * (expf(acc[j][2 * p] - dg[2 * p] - mh) + PEPS);
          v1 = RATIO * (expf(acc[j][2 * p + 1] - dg[2 * p + 1] - mh) + PEPS);
        }
        kt32[col * 33 + wave * 8 + lg * 2 + p] =
            (unsigned)f2bf(v0) | ((unsigned)f2bf(v1) << 16);
      }
    }
    __syncthreads();
    #pragma unroll
    for (int it = 0; it < 10; ++it) {
      int r = it * 32 + (tid >> 3);
      int cu = (tid & 7) * 4;
      uint4 o;
      o.x = kt32[r * 33 + cu + 0];
      o.y = kt32[r * 33 + cu + 1];
      o.z = kt32[r * 33 + cu + 2];
      o.w = kt32[r * 33 + cu + 3];
      *(uint4*)(out + ((long)h * NFP + r) * N_SEQ + m0 + cu * 2) = o;
    }
  }
}

// -------------------- ksum[h][j] = sum_n kpT[h][j][n] --------------------

__global__ __launch_bounds__(256) void ksum_kernel(const unsigned short* __restrict__ kpT,
                                                   float* __restrict__ ksum) {
  int h = blockIdx.y;
  int j = blockIdx.x * 4 + (threadIdx.x >> 6);
  int lane = threadIdx.x & 63;
  const unsigned short* row = kpT + ((long)h * NFP + j) * N_SEQ;
  float s = 0.f;
  #pragma unroll 4
  for (int it = 0; it < 16; ++it) {
    uint4 u = *(const uint4*)(row + (it * 64 + lane) * 8);
    const unsigned short* e = (const unsigned short*)&u;
    #pragma unroll
    for (int i = 0; i < 8; ++i) s += bf2f(e[i]);
  }
  #pragma unroll
  for (int m = 32; m >= 1; m >>= 1) s += __shfl_xor(s, m);
  if (lane == 0) ksum[h * NFP + j] = s;
}

// -------------------- ctx split-K MFMA: part[h][kc] = vT chunk x kpT chunk ----
// grid (32 kc, 8 h), block 256. C[64 d][320 j], K-chunk = 256.

__global__ __launch_bounds__(256) void ctx_mfma_kernel(
    const unsigned short* __restrict__ vT,   // [8][64][8192]
    const unsigned short* __restrict__ kpT,  // [8][320][8192]
    float* __restrict__ part) {              // [8][32][64][320]
  const int tid = threadIdx.x;
  const int wave = tid >> 6, lane = tid & 63;
  const int lr = lane & 15, lg = lane >> 4;
  const int wr = wave >> 1, wc = wave & 1;  // WM=32, WN=160
  const int kc = blockIdx.x, h = blockIdx.y;

  __shared__ uint4 a_s4[64 * 8];
  __shared__ uint4 b_s4[NFP * 8];

  const unsigned short* A = vT + (long)h * DHEAD * N_SEQ + kc * 256;
  const unsigned short* B = kpT + (long)h * NFP * N_SEQ + kc * 256;
  const int wbase = tid & 192;

  const unsigned short* asrc[2];
  #pragma unroll
  for (int e = 0; e < 2; ++e) {
    int chunk = e * 256 + tid;
    int r = chunk >> 3, c = chunk & 7;
    asrc[e] = A + (long)r * N_SEQ + (c ^ (r & 7)) * 8;
  }
  const unsigned short* bsrc[10];
  #pragma unroll
  for (int e = 0; e < 10; ++e) {
    int chunk = e * 256 + tid;
    int r = chunk >> 3, c = chunk & 7;
    bsrc[e] = B + (long)r * N_SEQ + (c ^ (r & 7)) * 8;
  }

  f32x4 acc[2][10] = {};

  for (int k0 = 0; k0 < 256; k0 += 64) {
    #pragma unroll
    for (int e = 0; e < 2; ++e) g2l16(asrc[e] + k0, a_s4 + e * 256 + wbase);
    #pragma unroll
    for (int e = 0; e < 10; ++e) g2l16(bsrc[e] + k0, b_s4 + e * 256 + wbase);
    __syncthreads();
    #pragma unroll
    for (int ks = 0; ks < 2; ++ks) {
      bf16x8 af[2], bv[10];
      #pragma unroll
      for (int i = 0; i < 2; ++i) {
        int r = wr * 32 + i * 16 + lr;
        af[i] = *(const bf16x8*)&a_s4[r * 8 + ((ks * 4 + lg) ^ (r & 7))];
      }
      #pragma unroll
      for (int j = 0; j < 10; ++j) {
        int r = wc * 160 + j * 16 + lr;
        bv[j] = *(const bf16x8*)&b_s4[r * 8 + ((ks * 4 + lg) ^ (r & 7))];
      }
      #pragma unroll
      for (int i = 0; i < 2; ++i)
        #pragma unroll
        for (int j = 0; j < 10; ++j)
          acc[i][j] = __builtin_amdgcn_mfma_f32_16x16x32_bf16(af[i], bv[j], acc[i][j], 0, 0, 0);
    }
    __syncthreads();
  }

  float* pbase = part + ((long)(h * 32 + kc)) * 64 * NFP;
  #pragma unroll
  for (int i = 0; i < 2; ++i) {
    #pragma unroll
    for (int j = 0; j < 10; ++j) {
      int gn = wc * 160 + j * 16 + lr;
      #pragma unroll
      for (int rg = 0; rg < 4; ++rg) {
        int gm = wr * 32 + i * 16 + lg * 4 + rg;
        pbase[(long)gm * NFP + gn] = acc[i][j][rg];
      }
    }
  }
}

// ctxpad[h][96][320]: rows 0-63 = sum of part, row 64 = ksum, rows 65-95 = 0.
__global__ void ctx_reduce_kernel(const float* __restrict__ part,
                                  const float* __restrict__ ksum,
                                  unsigned short* __restrict__ ctxpad) {
  int i = blockIdx.x * 256 + threadIdx.x;  // < 8*96*320 = 245760
  int h = i / (96 * NFP);
  int rem = i % (96 * NFP);
  int r = rem / NFP, j = rem % NFP;
  float s = 0.f;
  if (r < 64) {
    #pragma unroll 4
    for (int kc = 0; kc < 32; ++kc)
      s += part[((long)(h * 32 + kc)) * 64 * NFP + r * NFP + j];
  } else if (r == 64) {
    s = ksum[h * NFP + j];
  }
  ctxpad[i] = f2bf(s);
}

// -------------------- launch --------------------

extern "C" void kernel_launch(void* const* d_in, const int* in_sizes, int n_in,
                              void* d_out, int out_size, void* d_ws, size_t ws_size,
                              hipStream_t stream) {
  const float* x    = (const float*)d_in[0];
  const float* proj = (const float*)d_in[1];
  const float* ln1g = (const float*)d_in[2];
  const float* ln1b = (const float*)d_in[3];
  const float* wq   = (const float*)d_in[4];
  const float* wk   = (const float*)d_in[5];
  const float* wv   = (const float*)d_in[6];
  const float* wo   = (const float*)d_in[7];
  const float* wob  = (const float*)d_in[8];
  const float* ln2g = (const float*)d_in[9];
  const float* ln2b = (const float*)d_in[10];
  const float* w1   = (const float*)d_in[11];
  const float* b1   = (const float*)d_in[12];
  const float* w2   = (const float*)d_in[13];
  const float* b2   = (const float*)d_in[14];

  char* ws = (char*)d_ws;
  unsigned short* wtqkv = (unsigned short*)(ws + 0);
  unsigned short* wot   = (unsigned short*)(ws + 1572864);
  unsigned short* w1t   = (unsigned short*)(ws + 2097152);
  unsigned short* w2t   = (unsigned short*)(ws + 4194304);
  unsigned short* pb    = (unsigned short*)(ws + 6291456);
  unsigned short* h_bf  = (unsigned short*)(ws + 6332416);
  unsigned short* qkv   = (unsigned short*)(ws + 14721024);
  float* diag           = (float*)(ws + 39886848);
  unsigned short* qp    = (unsigned short*)(ws + 40411136);
  unsigned short* kpT   = (unsigned short*)(ws + 82354176);
  unsigned* mk          = (unsigned*)(ws + 124297216);
  unsigned short* vT    = (unsigned short*)(ws + 124297472);
  float* part           = (float*)(ws + 132686080);
  float* ksum           = (float*)(ws + 153657600);
  unsigned short* ctxpad= (unsigned short*)(ws + 153667840);
  unsigned short* gbf   = (unsigned short*)(ws + 130468096);
  unsigned short* attn  = h_bf;  // reuse (h_bf dead after QKV GEMM)
  unsigned short* h2    = qkv;   // reuse (qkv dead after phi/vtrans)
  float* xb             = (float*)d_out;

  dim3 blk(256);

  transpose_w_kernel<<<dim3(16, 16), dim3(32, 8), 0, stream>>>(wq, wtqkv, 512, 512);
  transpose_w_kernel<<<dim3(16, 16), dim3(32, 8), 0, stream>>>(wk, wtqkv + 262144, 512, 512);
  transpose_w_kernel<<<dim3(16, 16), dim3(32, 8), 0, stream>>>(wv, wtqkv + 524288, 512, 512);
  transpose_w_kernel<<<dim3(16, 16), dim3(32, 8), 0, stream>>>(wo, wot, 512, 512);
  transpose_w_kernel<<<dim3(64, 16), dim3(32, 8), 0, stream>>>(w1, w1t, 512, 2048);
  transpose_w_kernel<<<dim3(16, 64), dim3(32, 8), 0, stream>>>(w2, w2t, 2048, 512);
  projb_kernel<<<80, blk, 0, stream>>>(proj, pb);
  init_mk_kernel<<<1, 64, 0, stream>>>(mk);

  ln_kernel<<<N_SEQ, blk, 0, stream>>>(x, ln1g, ln1b, h_bf);

  gemm_kernel<128, 128, 64, 64, EPI_BF16><<<dim3(64, 4, 3), blk, 0, stream>>>(
      h_bf, 512, 0, wtqkv, 512, 262144, qkv, 512, 4194304, 512,
      nullptr, nullptr, 0);

  diag_kernel<<<512, blk, 0, stream>>>(qkv, diag);
  vtrans_kernel<<<dim3(1, 128, 8), blk, 0, stream>>>(qkv + 8388608, vT);

  phi_kernel<0><<<dim3(128, 1, 8), blk, 0, stream>>>(qkv, pb, qp, diag, mk);
  phi_kernel<1><<<dim3(128, 1, 8), blk, 0, stream>>>(qkv + 4194304, pb, kpT, diag + 65536, mk);
  phi_kernel<2><<<dim3(128, 1, 8), blk, 0, stream>>>(qkv + 4194304, pb, kpT, diag + 65536, mk);

  ksum_kernel<<<dim3(80, 8), blk, 0, stream>>>(kpT, ksum);
  ctx_mfma_kernel<<<dim3(32, 8), blk, 0, stream>>>(vT, kpT, part);
  ctx_reduce_kernel<<<960, blk, 0, stream>>>(part, ksum, ctxpad);

  gemm_kernel<128, 96, 32, 96, EPI_CTX><<<dim3(64, 1, 8), blk, 0, stream>>>(
      qp, NFP, (long)N_SEQ * NFP, ctxpad, NFP, 96 * NFP, attn, 512, 64, NFP,
      nullptr, nullptr, 0);

  gemm_kernel<128, 128, 64, 64, EPI_BIAS_RES_F32><<<dim3(64, 4, 1), blk, 0, stream>>>(
      attn, 512, 0, wot, 512, 0, xb, 512, 0, 512,
      wob, x, 512);

  ln_kernel<<<N_SEQ, blk, 0, stream>>>(xb, ln2g, ln2b, h2);

  gemm_kernel<128, 128, 64, 64, EPI_BIAS_GELU><<<dim3(64, 16, 1), blk, 0, stream>>>(
      h2, 512, 0, w1t, 512, 0, gbf, 2048, 0, 512,
      b1, nullptr, 0);

  gemm_kernel<128, 128, 64, 64, EPI_BIAS_RES_F32><<<dim3(64, 4, 1), blk, 0, stream>>>(
      gbf, 2048, 0, w2t, 2048, 0, d_out, 512, 0, 2048,
      b2, xb, 512);
}